// Round 11
// baseline (111.225 us; speedup 1.0000x reference)
//
#include <hip/hip_runtime.h>

typedef __fp16 h2 __attribute__((ext_vector_type(2)));

static __device__ __forceinline__ unsigned pkrtz(float a, float b) {
    union { h2 v; unsigned u; } cv;
    cv.v = __builtin_amdgcn_cvt_pkrtz(a, b);
    return cv.u;
}
static __device__ __forceinline__ h2 as_h2(unsigned u) {
    union { unsigned u; h2 v; } cv; cv.u = u; return cv.v;
}

// ---- prep: pack weights into f16-pair dwords in d_ws -------------------------
// Layout (dwords):
//   [j*6 + i]      i<5 : (W1[j][2i], W1[j][2i+1]) f16 pair       (j in 0..39)
//   [j*6 + 5]          : b1[j] as f32 bits
//   [240 + p*4+o]      : (W2[o][2p], W2[o][2p+1]) f16 pair       (p in 0..19)
//   [320 + o]          : b2[o] as f32 bits
__global__ void prep_kernel(const float* __restrict__ W1, const float* __restrict__ b1,
                            const float* __restrict__ W2, const float* __restrict__ b2,
                            unsigned* __restrict__ ws) {
    const int t = threadIdx.x;
    if (t < 40) {
        #pragma unroll
        for (int i = 0; i < 5; ++i)
            ws[t * 6 + i] = pkrtz(W1[t * 10 + 2 * i], W1[t * 10 + 2 * i + 1]);
        ws[t * 6 + 5] = __float_as_uint(b1[t]);
    } else if (t < 60) {
        const int p = t - 40;
        #pragma unroll
        for (int o = 0; o < 4; ++o)
            ws[240 + p * 4 + o] = pkrtz(W2[o * 40 + 2 * p], W2[o * 40 + 2 * p + 1]);
    } else if (t < 64) {
        ws[320 + (t - 60)] = __float_as_uint(b2[t - 60]);
    }
}

#define TPB 256

// ---- main: 2 edges per thread; weights shared across the pair ----------------
__global__ __launch_bounds__(TPB) void edge_mlp_x2_kernel(
    const float* __restrict__ x,
    const float* __restrict__ w,
    const int* __restrict__ src,
    const int* __restrict__ dst,
    const unsigned* __restrict__ W,
    float* __restrict__ w_out,
    float* __restrict__ e_tilde,
    int E)
{
    const int g  = blockIdx.x * TPB + threadIdx.x;   // edge-pair index
    const int e0 = 2 * g;
    const bool fa = (e0 < E);
    const bool fb = (e0 + 1 < E);

    float ma0 = 0.f, ma1 = 0.f, ma2 = 0.f;
    float mb0 = 0.f, mb1 = 0.f, mb2 = 0.f;
    h2 va0 = as_h2(0), va1 = as_h2(0), va2 = as_h2(0), va3 = as_h2(0), va4 = as_h2(0);
    h2 vb0 = as_h2(0), vb1 = as_h2(0), vb2 = as_h2(0), vb3 = as_h2(0), vb4 = as_h2(0);

    if (fb) {
        // paired index loads + 12 independent gathers in flight together
        const int2 sp = ((const int2*)src)[g];
        const int2 dp = ((const int2*)dst)[g];
        const float as0 = x[3 * sp.x], as1 = x[3 * sp.x + 1], as2 = x[3 * sp.x + 2];
        const float bs0 = x[3 * sp.y], bs1 = x[3 * sp.y + 1], bs2 = x[3 * sp.y + 2];
        const float ad0 = x[3 * dp.x], ad1 = x[3 * dp.x + 1], ad2 = x[3 * dp.x + 2];
        const float bd0 = x[3 * dp.y], bd1 = x[3 * dp.y + 1], bd2 = x[3 * dp.y + 2];
        const float4 wa = ((const float4*)w)[e0];
        const float4 wb = ((const float4*)w)[e0 + 1];
        ma0 = as0; ma1 = as1; ma2 = as2;
        mb0 = bs0; mb1 = bs1; mb2 = bs2;
        va0 = as_h2(pkrtz(as0, as1)); va1 = as_h2(pkrtz(as2, ad0));
        va2 = as_h2(pkrtz(ad1, ad2)); va3 = as_h2(pkrtz(wa.x, wa.y));
        va4 = as_h2(pkrtz(wa.z, wa.w));
        vb0 = as_h2(pkrtz(bs0, bs1)); vb1 = as_h2(pkrtz(bs2, bd0));
        vb2 = as_h2(pkrtz(bd1, bd2)); vb3 = as_h2(pkrtz(wb.x, wb.y));
        vb4 = as_h2(pkrtz(wb.z, wb.w));
    } else if (fa) {
        const int si = src[e0], di = dst[e0];
        const float as0 = x[3 * si], as1 = x[3 * si + 1], as2 = x[3 * si + 2];
        const float ad0 = x[3 * di], ad1 = x[3 * di + 1], ad2 = x[3 * di + 2];
        const float4 wa = ((const float4*)w)[e0];
        ma0 = as0; ma1 = as1; ma2 = as2;
        va0 = as_h2(pkrtz(as0, as1)); va1 = as_h2(pkrtz(as2, ad0));
        va2 = as_h2(pkrtz(ad1, ad2)); va3 = as_h2(pkrtz(wa.x, wa.y));
        va4 = as_h2(pkrtz(wa.z, wa.w));
    }

    float oa0 = __uint_as_float(W[320]);
    float oa1 = __uint_as_float(W[321]);
    float oa2 = __uint_as_float(W[322]);
    float oa3 = __uint_as_float(W[323]);
    float ob0 = oa0, ob1 = oa1, ob2 = oa2, ob3 = oa3;

    #pragma unroll
    for (int jp = 0; jp < 20; ++jp) {
        const int j0 = 2 * jp, j1 = 2 * jp + 1;
        // each weight dword loaded once, used by both edges
        const h2 w00 = as_h2(W[j0 * 6 + 0]);
        const h2 w01 = as_h2(W[j0 * 6 + 1]);
        const h2 w02 = as_h2(W[j0 * 6 + 2]);
        const h2 w03 = as_h2(W[j0 * 6 + 3]);
        const h2 w04 = as_h2(W[j0 * 6 + 4]);
        const h2 w10 = as_h2(W[j1 * 6 + 0]);
        const h2 w11 = as_h2(W[j1 * 6 + 1]);
        const h2 w12 = as_h2(W[j1 * 6 + 2]);
        const h2 w13 = as_h2(W[j1 * 6 + 3]);
        const h2 w14 = as_h2(W[j1 * 6 + 4]);
        const float bj0 = __uint_as_float(W[j0 * 6 + 5]);
        const float bj1 = __uint_as_float(W[j1 * 6 + 5]);

        float h0a = bj0, h1a = bj1, h0b = bj0, h1b = bj1;
        h0a = __builtin_amdgcn_fdot2(va0, w00, h0a, false);
        h0b = __builtin_amdgcn_fdot2(vb0, w00, h0b, false);
        h1a = __builtin_amdgcn_fdot2(va0, w10, h1a, false);
        h1b = __builtin_amdgcn_fdot2(vb0, w10, h1b, false);
        h0a = __builtin_amdgcn_fdot2(va1, w01, h0a, false);
        h0b = __builtin_amdgcn_fdot2(vb1, w01, h0b, false);
        h1a = __builtin_amdgcn_fdot2(va1, w11, h1a, false);
        h1b = __builtin_amdgcn_fdot2(vb1, w11, h1b, false);
        h0a = __builtin_amdgcn_fdot2(va2, w02, h0a, false);
        h0b = __builtin_amdgcn_fdot2(vb2, w02, h0b, false);
        h1a = __builtin_amdgcn_fdot2(va2, w12, h1a, false);
        h1b = __builtin_amdgcn_fdot2(vb2, w12, h1b, false);
        h0a = __builtin_amdgcn_fdot2(va3, w03, h0a, false);
        h0b = __builtin_amdgcn_fdot2(vb3, w03, h0b, false);
        h1a = __builtin_amdgcn_fdot2(va3, w13, h1a, false);
        h1b = __builtin_amdgcn_fdot2(vb3, w13, h1b, false);
        h0a = __builtin_amdgcn_fdot2(va4, w04, h0a, false);
        h0b = __builtin_amdgcn_fdot2(vb4, w04, h0b, false);
        h1a = __builtin_amdgcn_fdot2(va4, w14, h1a, false);
        h1b = __builtin_amdgcn_fdot2(vb4, w14, h1b, false);

        h0a = fmaxf(h0a, 0.f); h1a = fmaxf(h1a, 0.f);
        h0b = fmaxf(h0b, 0.f); h1b = fmaxf(h1b, 0.f);
        const h2 hpa = as_h2(pkrtz(h0a, h1a));
        const h2 hpb = as_h2(pkrtz(h0b, h1b));

        const h2 c0 = as_h2(W[240 + jp * 4 + 0]);
        const h2 c1 = as_h2(W[240 + jp * 4 + 1]);
        const h2 c2 = as_h2(W[240 + jp * 4 + 2]);
        const h2 c3 = as_h2(W[240 + jp * 4 + 3]);
        oa0 = __builtin_amdgcn_fdot2(hpa, c0, oa0, false);
        ob0 = __builtin_amdgcn_fdot2(hpb, c0, ob0, false);
        oa1 = __builtin_amdgcn_fdot2(hpa, c1, oa1, false);
        ob1 = __builtin_amdgcn_fdot2(hpb, c1, ob1, false);
        oa2 = __builtin_amdgcn_fdot2(hpa, c2, oa2, false);
        ob2 = __builtin_amdgcn_fdot2(hpb, c2, ob2, false);
        oa3 = __builtin_amdgcn_fdot2(hpa, c3, oa3, false);
        ob3 = __builtin_amdgcn_fdot2(hpb, c3, ob3, false);
    }

    if (fb) {
        // w_out: two contiguous float4 per thread
        ((float4*)w_out)[e0]     = make_float4(oa0, oa1, oa2, oa3);
        ((float4*)w_out)[e0 + 1] = make_float4(ob0, ob1, ob2, ob3);
        // e_tilde: 14 contiguous floats, 8B-aligned -> 7 float2 stores
        float2* et = (float2*)(e_tilde + (long long)g * 14);
        et[0] = make_float2(ma0, ma1);
        et[1] = make_float2(ma2, oa0);
        et[2] = make_float2(oa1, oa2);
        et[3] = make_float2(oa3, mb0);
        et[4] = make_float2(mb1, mb2);
        et[5] = make_float2(ob0, ob1);
        et[6] = make_float2(ob2, ob3);
    } else if (fa) {
        ((float4*)w_out)[e0] = make_float4(oa0, oa1, oa2, oa3);
        float* et = e_tilde + (long long)e0 * 7;
        et[0] = ma0; et[1] = ma1; et[2] = ma2;
        et[3] = oa0; et[4] = oa1; et[5] = oa2; et[6] = oa3;
    }
}

extern "C" void kernel_launch(void* const* d_in, const int* in_sizes, int n_in,
                              void* d_out, int out_size, void* d_ws, size_t ws_size,
                              hipStream_t stream) {
    const float* x  = (const float*)d_in[0];
    const float* w  = (const float*)d_in[1];
    const float* W1 = (const float*)d_in[2];
    const float* b1 = (const float*)d_in[3];
    const float* W2 = (const float*)d_in[4];
    const float* b2 = (const float*)d_in[5];
    const int* src  = (const int*)d_in[6];
    const int* dst  = (const int*)d_in[7];

    const int E = in_sizes[6];

    float* w_out   = (float*)d_out;
    float* e_tilde = w_out + (size_t)E * 4;
    unsigned* ws   = (unsigned*)d_ws;

    prep_kernel<<<1, 64, 0, stream>>>(W1, b1, W2, b2, ws);

    const int npairs  = (E + 1) / 2;
    const int nblocks = (npairs + TPB - 1) / TPB;
    edge_mlp_x2_kernel<<<nblocks, TPB, 0, stream>>>(
        x, w, src, dst, ws, w_out, e_tilde, E);
}

// Round 13
// 98.469 us; speedup vs baseline: 1.1295x; 1.1295x over previous
//
#include <hip/hip_runtime.h>

typedef __fp16 h2 __attribute__((ext_vector_type(2)));
typedef float f4 __attribute__((ext_vector_type(4)));

static __device__ __forceinline__ unsigned pkrtz(float a, float b) {
    union { h2 v; unsigned u; } cv;
    cv.v = __builtin_amdgcn_cvt_pkrtz(a, b);
    return cv.u;
}
static __device__ __forceinline__ h2 as_h2(unsigned u) {
    union { unsigned u; h2 v; } cv; cv.u = u; return cv.v;
}

// ---- prep: pack weights into f16-pair dwords in d_ws -------------------------
// Layout (dwords):
//   [j*6 + i]      i<5 : (W1[j][2i], W1[j][2i+1]) f16 pair       (j in 0..39)
//   [j*6 + 5]          : b1[j] as f32 bits
//   [240 + p*4+o]      : (W2[o][2p], W2[o][2p+1]) f16 pair       (p in 0..19)
//   [320 + o]          : b2[o] as f32 bits
__global__ void prep_kernel(const float* __restrict__ W1, const float* __restrict__ b1,
                            const float* __restrict__ W2, const float* __restrict__ b2,
                            unsigned* __restrict__ ws) {
    const int t = threadIdx.x;
    if (t < 40) {
        #pragma unroll
        for (int i = 0; i < 5; ++i)
            ws[t * 6 + i] = pkrtz(W1[t * 10 + 2 * i], W1[t * 10 + 2 * i + 1]);
        ws[t * 6 + 5] = __float_as_uint(b1[t]);
    } else if (t < 60) {
        const int p = t - 40;
        #pragma unroll
        for (int o = 0; o < 4; ++o)
            ws[240 + p * 4 + o] = pkrtz(W2[o * 40 + 2 * p], W2[o * 40 + 2 * p + 1]);
    } else if (t < 64) {
        ws[320 + (t - 60)] = __float_as_uint(b2[t - 60]);
    }
}

// ---- main: 1 thread/edge; weights via SGPR; nt hints on touch-once streams ---
#define TPB 256

__global__ __launch_bounds__(TPB) void edge_mlp_nt_kernel(
    const float* __restrict__ x,
    const float* __restrict__ w,
    const int* __restrict__ src,
    const int* __restrict__ dst,
    const unsigned* __restrict__ W,   // packed weights (uniform access -> SGPR)
    float* __restrict__ w_out,
    float* __restrict__ e_tilde,
    int E)
{
    __shared__ float s_et[4][64 * 7];   // per-wave e_tilde staging

    const int t    = threadIdx.x;
    const int wave = t >> 6;
    const int lane = t & 63;
    const int e    = blockIdx.x * TPB + t;

    float m0 = 0.f, m1 = 0.f, m2 = 0.f;
    h2 vm0 = as_h2(0), vm1 = as_h2(0), vm2 = as_h2(0), vm3 = as_h2(0), vm4 = as_h2(0);

    if (e < E) {
        // touch-once streams: non-temporal (evict-first, keep x-table in L2)
        const int si = __builtin_nontemporal_load(src + e);
        const int di = __builtin_nontemporal_load(dst + e);
        // x-table gathers: normal cached loads (reused across edges)
        m0 = x[3 * si]; m1 = x[3 * si + 1]; m2 = x[3 * si + 2];
        const float d0 = x[3 * di], d1 = x[3 * di + 1], d2 = x[3 * di + 2];
        const f4 wv = __builtin_nontemporal_load((const f4*)w + e);
        vm0 = as_h2(pkrtz(m0, m1));
        vm1 = as_h2(pkrtz(m2, d0));
        vm2 = as_h2(pkrtz(d1, d2));
        vm3 = as_h2(pkrtz(wv.x, wv.y));
        vm4 = as_h2(pkrtz(wv.z, wv.w));
    }

    float o0 = __uint_as_float(W[320]);
    float o1 = __uint_as_float(W[321]);
    float o2 = __uint_as_float(W[322]);
    float o3 = __uint_as_float(W[323]);

    #pragma unroll
    for (int jp = 0; jp < 20; ++jp) {
        const int j0 = 2 * jp, j1 = 2 * jp + 1;
        float h0v = __uint_as_float(W[j0 * 6 + 5]);
        float h1v = __uint_as_float(W[j1 * 6 + 5]);
        h0v = __builtin_amdgcn_fdot2(vm0, as_h2(W[j0 * 6 + 0]), h0v, false);
        h1v = __builtin_amdgcn_fdot2(vm0, as_h2(W[j1 * 6 + 0]), h1v, false);
        h0v = __builtin_amdgcn_fdot2(vm1, as_h2(W[j0 * 6 + 1]), h0v, false);
        h1v = __builtin_amdgcn_fdot2(vm1, as_h2(W[j1 * 6 + 1]), h1v, false);
        h0v = __builtin_amdgcn_fdot2(vm2, as_h2(W[j0 * 6 + 2]), h0v, false);
        h1v = __builtin_amdgcn_fdot2(vm2, as_h2(W[j1 * 6 + 2]), h1v, false);
        h0v = __builtin_amdgcn_fdot2(vm3, as_h2(W[j0 * 6 + 3]), h0v, false);
        h1v = __builtin_amdgcn_fdot2(vm3, as_h2(W[j1 * 6 + 3]), h1v, false);
        h0v = __builtin_amdgcn_fdot2(vm4, as_h2(W[j0 * 6 + 4]), h0v, false);
        h1v = __builtin_amdgcn_fdot2(vm4, as_h2(W[j1 * 6 + 4]), h1v, false);
        h0v = fmaxf(h0v, 0.f);
        h1v = fmaxf(h1v, 0.f);
        const h2 hp = as_h2(pkrtz(h0v, h1v));
        o0 = __builtin_amdgcn_fdot2(hp, as_h2(W[240 + jp * 4 + 0]), o0, false);
        o1 = __builtin_amdgcn_fdot2(hp, as_h2(W[240 + jp * 4 + 1]), o1, false);
        o2 = __builtin_amdgcn_fdot2(hp, as_h2(W[240 + jp * 4 + 2]), o2, false);
        o3 = __builtin_amdgcn_fdot2(hp, as_h2(W[240 + jp * 4 + 3]), o3, false);
    }

    if (e < E) {
        f4 ov; ov.x = o0; ov.y = o1; ov.z = o2; ov.w = o3;
        __builtin_nontemporal_store(ov, (f4*)w_out + e);
    }

    // e_tilde staging -> coalesced nt stores
    float* sw = s_et[wave];
    sw[lane * 7 + 0] = m0;
    sw[lane * 7 + 1] = m1;
    sw[lane * 7 + 2] = m2;
    sw[lane * 7 + 3] = o0;
    sw[lane * 7 + 4] = o1;
    sw[lane * 7 + 5] = o2;
    sw[lane * 7 + 6] = o3;
    __syncthreads();

    const int base_e  = blockIdx.x * TPB + wave * 64;
    const int nvalid  = (E - base_e < 64 ? (E - base_e) : 64) * 7;
    const long long fbase = (long long)base_e * 7;
    #pragma unroll
    for (int k = 0; k < 7; ++k) {
        const int idx = lane + 64 * k;
        if (idx < nvalid)
            __builtin_nontemporal_store(sw[idx], e_tilde + fbase + idx);
    }
}

extern "C" void kernel_launch(void* const* d_in, const int* in_sizes, int n_in,
                              void* d_out, int out_size, void* d_ws, size_t ws_size,
                              hipStream_t stream) {
    const float* x  = (const float*)d_in[0];
    const float* w  = (const float*)d_in[1];
    const float* W1 = (const float*)d_in[2];
    const float* b1 = (const float*)d_in[3];
    const float* W2 = (const float*)d_in[4];
    const float* b2 = (const float*)d_in[5];
    const int* src  = (const int*)d_in[6];
    const int* dst  = (const int*)d_in[7];

    const int E = in_sizes[6];

    float* w_out   = (float*)d_out;
    float* e_tilde = w_out + (size_t)E * 4;
    unsigned* ws   = (unsigned*)d_ws;

    prep_kernel<<<1, 64, 0, stream>>>(W1, b1, W2, b2, ws);

    const int nblocks = (E + TPB - 1) / TPB;
    edge_mlp_nt_kernel<<<nblocks, TPB, 0, stream>>>(
        x, w, src, dst, ws, w_out, e_tilde, E);
}